// Round 1
// baseline (897.820 us; speedup 1.0000x reference)
//
#include <hip/hip_runtime.h>

#define TT 256   // T
#define BBATCH 512   // B
#define HH 64
#define NG 256   // 4*H
#define KIN 128  // input width for both layers

typedef _Float16 half4v __attribute__((ext_vector_type(4)));
typedef _Float16 half8v __attribute__((ext_vector_type(8)));
typedef float float4v __attribute__((ext_vector_type(4)));

__device__ __forceinline__ float sigmoid_(float x){ return 1.f/(1.f+__expf(-x)); }
__device__ __forceinline__ float tanh_(float x){
  float xc = fminf(fmaxf(x,-9.f),9.f);
  float e = __expf(2.f*xc);
  return (e-1.f)/(e+1.f);
}

__device__ __forceinline__ half4v ld4h(const float* p){
  float4v v = *reinterpret_cast<const float4v*>(p);
  half4v h; h[0]=(_Float16)v[0]; h[1]=(_Float16)v[1]; h[2]=(_Float16)v[2]; h[3]=(_Float16)v[3];
  return h;
}
__device__ __forceinline__ half4v ld4h(const _Float16* p){
  return *reinterpret_cast<const half4v*>(p);
}

// C[m][n] = sum_k A[m][k]*W[n][k] + bias[n]
// A: M x 128 (AT = float or _Float16), W: 256 x 128 fp32 row-major, C: M x 256 fp32
// block: 256 thr / 4 waves; tile M=64 x N=256; K chunks of 64; fp16 MFMA 16x16x32
template<typename AT>
__global__ __launch_bounds__(256)
void gemm_xg(const AT* __restrict__ A, const float* __restrict__ W,
             const float* __restrict__ bias, float* __restrict__ C)
{
  __shared__ __align__(16) _Float16 aL[64][72];   // +8 halves pad (16B) -> conflict-free b128 frag reads
  __shared__ __align__(16) _Float16 wL[256][72];
  const int tid  = threadIdx.x;
  const int wave = tid >> 6;
  const int lane = tid & 63;
  const int lr   = lane & 15;   // row/col within 16x16 tile
  const int kg   = lane >> 4;   // k-group (8 consecutive k per group)
  const size_t m0 = (size_t)blockIdx.x * 64;

  float4v acc[4][4];
  #pragma unroll
  for (int a=0;a<4;a++)
    #pragma unroll
    for (int b=0;b<4;b++)
      acc[a][b] = float4v{0.f,0.f,0.f,0.f};

  for (int kc = 0; kc < KIN; kc += 64) {
    // A chunk: 64 rows x 64 k  (1024 vec4 / 256 thr = 4 each)
    #pragma unroll
    for (int q=0;q<4;q++){
      int fi = tid + q*256;
      int r = fi >> 4, c4 = (fi & 15)*4;
      *reinterpret_cast<half4v*>(&aL[r][c4]) = ld4h(&A[(m0+(size_t)r)*KIN + kc + c4]);
    }
    // W chunk: 256 rows x 64 k (4096 vec4 / 256 thr = 16 each); layout [n][k] matches B-frag reads
    #pragma unroll
    for (int q=0;q<16;q++){
      int fi = tid + q*256;
      int n = fi >> 4, c4 = (fi & 15)*4;
      *reinterpret_cast<half4v*>(&wL[n][c4]) = ld4h(&W[(size_t)n*KIN + kc + c4]);
    }
    __syncthreads();
    #pragma unroll
    for (int ks=0; ks<64; ks+=32){
      half8v af[4], bf[4];
      #pragma unroll
      for (int rt=0;rt<4;rt++)   // A[row=lr in tile rt][k = ks + kg*8 + j]
        af[rt] = *reinterpret_cast<const half8v*>(&aL[rt*16+lr][ks + kg*8]);
      #pragma unroll
      for (int ct=0;ct<4;ct++)   // B[k][col] = W[col][k], wave owns cols [wave*64, wave*64+64)
        bf[ct] = *reinterpret_cast<const half8v*>(&wL[wave*64 + ct*16 + lr][ks + kg*8]);
      #pragma unroll
      for (int rt=0;rt<4;rt++)
        #pragma unroll
        for (int ct=0;ct<4;ct++)
          acc[rt][ct] = __builtin_amdgcn_mfma_f32_16x16x32_f16(af[rt], bf[ct], acc[rt][ct], 0,0,0);
    }
    __syncthreads();
  }
  // C/D layout: col = lane&15, row = (lane>>4)*4 + i  (m89-verified)
  #pragma unroll
  for (int ct=0;ct<4;ct++){
    const int col = wave*64 + ct*16 + lr;
    const float bv = bias[col];
    #pragma unroll
    for (int rt=0;rt<4;rt++){
      const size_t rbase = m0 + rt*16 + kg*4;
      #pragma unroll
      for (int i=0;i<4;i++)
        C[(rbase+(size_t)i)*NG + col] = acc[rt][ct][i] + bv;
    }
  }
}

// One LSTM scan direction. xg: (B*T, 256) fp32 precomputed preacts (incl bias).
// DIR: 0 = forward, 1 = reverse.  MODE: 0 = write h per t into x1 (fp16) at col_off; 1 = write only final h.
// grid: B/2 blocks; block 256 threads; thread t = gate column; 2 batch rows per block.
template<int DIR, int MODE>
__global__ __launch_bounds__(256)
void lstm_scan(const float* __restrict__ xg, const float* __restrict__ w_hh,
               _Float16* __restrict__ x1out, int col_off, float* __restrict__ hfin)
{
  const int tid = threadIdx.x;
  const int r0  = blockIdx.x * 2;
  __shared__ __align__(16) float h_s[2][64];
  __shared__ __align__(16) float act_s[2][256];

  // w_hh row for this gate column into registers (64 VGPR)
  float w[64];
  #pragma unroll
  for (int kk=0;kk<16;kk++)
    *reinterpret_cast<float4v*>(&w[kk*4]) =
        *reinterpret_cast<const float4v*>(&w_hh[(size_t)tid*64 + kk*4]);

  if (tid < 128) h_s[tid>>6][tid&63] = 0.f;
  float c_r = 0.f, h_last = 0.f;
  __syncthreads();

  const float* xg0 = xg + ((size_t)r0 * TT)*NG + tid;
  const float* xg1 = xg + ((size_t)(r0+1) * TT)*NG + tid;

  // 2-deep prefetch of xg (it is L3-resident; ~400-500cy latency)
  int t0 = DIR ? (TT-1) : 0;
  int t1 = DIR ? (TT-2) : 1;
  float cur0 = xg0[(size_t)t0*NG];
  float cur1 = xg1[(size_t)t0*NG];
  float nx0  = xg0[(size_t)t1*NG];
  float nx1  = xg1[(size_t)t1*NG];

  for (int tt=0; tt<TT; tt++) {
    const int t  = DIR ? (TT-1-tt) : tt;
    const int tn = (tt+2 < TT) ? (tt+2) : (TT-1);
    const int tp = DIR ? (TT-1-tn) : tn;
    float pf0 = xg0[(size_t)tp*NG];
    float pf1 = xg1[(size_t)tp*NG];

    // gate preact: cur + sum_k w[k]*h[k]  (4 partial chains per row)
    float p0a=0.f,p0b=0.f,p0c=0.f,p0d=0.f, p1a=0.f,p1b=0.f,p1c=0.f,p1d=0.f;
    #pragma unroll
    for (int kk=0;kk<16;kk++){
      float4v h0 = *reinterpret_cast<float4v*>(&h_s[0][kk*4]);
      float4v h1 = *reinterpret_cast<float4v*>(&h_s[1][kk*4]);
      p0a += w[kk*4+0]*h0[0]; p0b += w[kk*4+1]*h0[1];
      p0c += w[kk*4+2]*h0[2]; p0d += w[kk*4+3]*h0[3];
      p1a += w[kk*4+0]*h1[0]; p1b += w[kk*4+1]*h1[1];
      p1c += w[kk*4+2]*h1[2]; p1d += w[kk*4+3]*h1[3];
    }
    float a0 = cur0 + ((p0a+p0b)+(p0c+p0d));
    float a1 = cur1 + ((p1a+p1b)+(p1c+p1d));

    const int grp = tid >> 6;           // 0:i 1:f 2:g 3:o  -- wave-uniform branch
    float v0 = (grp==2) ? tanh_(a0) : sigmoid_(a0);
    float v1 = (grp==2) ? tanh_(a1) : sigmoid_(a1);
    act_s[0][tid] = v0;
    act_s[1][tid] = v1;
    __syncthreads();

    if (tid < 128) {
      const int r = tid>>6, j = tid&63;
      float iv = act_s[r][j], fv = act_s[r][64+j], gv = act_s[r][128+j], ov = act_s[r][192+j];
      c_r = fv*c_r + iv*gv;
      float h = ov * tanh_(c_r);
      h_last = h;
      h_s[r][j] = h;
      if constexpr (MODE==0)
        x1out[((size_t)(r0+r)*TT + t)*128 + col_off + j] = (_Float16)h;
    }
    __syncthreads();
    cur0 = nx0; cur1 = nx1; nx0 = pf0; nx1 = pf1;
  }
  if constexpr (MODE==1) {
    if (tid < 128)
      hfin[(size_t)(r0 + (tid>>6))*64 + (tid&63)] = h_last;
  }
}

// Layer-1 reverse needs only its t=T-1 output = ONE step from zero state on x1[:,T-1].
// Fuse that step + final FC. grid: B blocks.
__global__ __launch_bounds__(256)
void final_fuse(const _Float16* __restrict__ x1, const float* __restrict__ w_ih,
                const float* __restrict__ bvec, const float* __restrict__ hfin,
                const float* __restrict__ fcw, const float* __restrict__ fcb,
                float* __restrict__ out)
{
  const int b = blockIdx.x, tid = threadIdx.x;
  __shared__ float xs[128];
  __shared__ float act[256];
  __shared__ float hall[128];
  if (tid < 128) xs[tid] = (float)x1[((size_t)b*TT + (TT-1))*128 + tid];
  __syncthreads();
  float a = bvec[tid];
  #pragma unroll
  for (int kk=0;kk<32;kk++){
    float4v wv = *reinterpret_cast<const float4v*>(&w_ih[(size_t)tid*128 + kk*4]);
    a += wv[0]*xs[kk*4] + wv[1]*xs[kk*4+1] + wv[2]*xs[kk*4+2] + wv[3]*xs[kk*4+3];
  }
  const int grp = tid>>6;
  act[tid] = (grp==2) ? tanh_(a) : sigmoid_(a);
  __syncthreads();
  if (tid < 64) {
    float c = act[tid]*act[128+tid];        // c = i*g (c0 = 0, f term vanishes)
    float h = act[192+tid]*tanh_(c);        // h = o*tanh(c)
    hall[64+tid] = h;
    hall[tid] = hfin[(size_t)b*64 + tid];
  }
  __syncthreads();
  if (tid < 3) {
    float acc2 = fcb[tid];
    for (int k=0;k<128;k++) acc2 += fcw[(size_t)tid*128 + k]*hall[k];
    out[(size_t)b*3 + tid] = acc2;
  }
}

extern "C" void kernel_launch(void* const* d_in, const int* in_sizes, int n_in,
                              void* d_out, int out_size, void* d_ws, size_t ws_size,
                              hipStream_t stream) {
  const float* x        = (const float*)d_in[0];
  const float* w_ih_l0f = (const float*)d_in[1];
  const float* w_hh_l0f = (const float*)d_in[2];
  const float* b_l0f    = (const float*)d_in[3];
  const float* w_ih_l0r = (const float*)d_in[4];
  const float* w_hh_l0r = (const float*)d_in[5];
  const float* b_l0r    = (const float*)d_in[6];
  const float* w_ih_l1f = (const float*)d_in[7];
  const float* w_hh_l1f = (const float*)d_in[8];
  const float* b_l1f    = (const float*)d_in[9];
  const float* w_ih_l1r = (const float*)d_in[10];
  const float* b_l1r    = (const float*)d_in[12];
  const float* fc_w     = (const float*)d_in[13];
  const float* fc_b     = (const float*)d_in[14];
  float* out = (float*)d_out;

  // workspace layout
  const size_t XG_BYTES = (size_t)BBATCH*TT*NG*4;     // 134,217,728
  const size_t X1_BYTES = (size_t)BBATCH*TT*128*2;    //  33,554,432
  const size_t HF_BYTES = (size_t)BBATCH*64*4;        //     131,072
  if (ws_size < XG_BYTES + X1_BYTES + HF_BYTES) return;
  float*     xg   = (float*)d_ws;
  _Float16*  x1   = (_Float16*)((char*)d_ws + XG_BYTES);
  float*     hfin = (float*)((char*)d_ws + XG_BYTES + X1_BYTES);

  const int MBLK = (BBATCH*TT)/64;  // 2048

  // layer 0 forward
  gemm_xg<float><<<MBLK, 256, 0, stream>>>(x, w_ih_l0f, b_l0f, xg);
  lstm_scan<0,0><<<BBATCH/2, 256, 0, stream>>>(xg, w_hh_l0f, x1, 0, nullptr);
  // layer 0 reverse
  gemm_xg<float><<<MBLK, 256, 0, stream>>>(x, w_ih_l0r, b_l0r, xg);
  lstm_scan<1,0><<<BBATCH/2, 256, 0, stream>>>(xg, w_hh_l0r, x1, 64, nullptr);
  // layer 1 forward (only final h needed)
  gemm_xg<_Float16><<<MBLK, 256, 0, stream>>>(x1, w_ih_l1f, b_l1f, xg);
  lstm_scan<0,1><<<BBATCH/2, 256, 0, stream>>>(xg, w_hh_l1f, nullptr, 0, hfin);
  // layer 1 reverse one-step + FC
  final_fuse<<<BBATCH, 256, 0, stream>>>(x1, w_ih_l1r, b_l1r, hfin, fc_w, fc_b, out);
}

// Round 2
// 489.525 us; speedup vs baseline: 1.8341x; 1.8341x over previous
//
#include <hip/hip_runtime.h>

#define TT 256   // T
#define BB 512   // B
#define NG 256   // 4*H
#define KIN 128  // input width for both layers

typedef _Float16 half2v __attribute__((ext_vector_type(2)));
typedef _Float16 half4v __attribute__((ext_vector_type(4)));
typedef _Float16 half8v __attribute__((ext_vector_type(8)));
typedef float float4v __attribute__((ext_vector_type(4)));

__device__ __forceinline__ float sigmoid_(float x){ return 1.f/(1.f+__expf(-x)); }
__device__ __forceinline__ float tanh_(float x){
  float xc = fminf(fmaxf(x,-9.f),9.f);
  float e = __expf(2.f*xc);
  return (e-1.f)/(e+1.f);
}

#if __has_builtin(__builtin_amdgcn_fdot2)
__device__ __forceinline__ float fdot2_(half2v a, half2v b, float c){
  return __builtin_amdgcn_fdot2(a, b, c, false);
}
#else
__device__ __forceinline__ float fdot2_(half2v a, half2v b, float c){
  return c + (float)a[0]*(float)b[0] + (float)a[1]*(float)b[1];
}
#endif

__device__ __forceinline__ half4v ld4h(const float* p){
  float4v v = *reinterpret_cast<const float4v*>(p);
  half4v h; h[0]=(_Float16)v[0]; h[1]=(_Float16)v[1]; h[2]=(_Float16)v[2]; h[3]=(_Float16)v[3];
  return h;
}

// ---- one-shot weight conversion fp32 -> fp16 into ws pool ----
// halves offsets: wih_l0f 0, wih_l0r 32768, wih_l1f 65536,
//                 whh_l0f 98304, whh_l0r 114688, whh_l1f 131072  (total 147456)
__global__ __launch_bounds__(256)
void conv_weights(const float* __restrict__ s0, const float* __restrict__ s1,
                  const float* __restrict__ s2, const float* __restrict__ s3,
                  const float* __restrict__ s4, const float* __restrict__ s5,
                  _Float16* __restrict__ dst)
{
  const int bid = blockIdx.x, tid = threadIdx.x;
  const float* src; int off, idx;
  if (bid < 128)      { src=s0; off=0;      idx=bid*256+tid; }
  else if (bid < 256) { src=s1; off=32768;  idx=(bid-128)*256+tid; }
  else if (bid < 384) { src=s2; off=65536;  idx=(bid-256)*256+tid; }
  else if (bid < 448) { src=s3; off=98304;  idx=(bid-384)*256+tid; }
  else if (bid < 512) { src=s4; off=114688; idx=(bid-448)*256+tid; }
  else                { src=s5; off=131072; idx=(bid-512)*256+tid; }
  dst[off+idx] = (_Float16)src[idx];
}

// C[m][n] = sum_k A[m][k]*W[n][k] + bias[n], written fp16.
// A: M x 128 (float or fp16), W16: 256x128 fp16 row-major.
// block 256 thr / 4 waves; tile M=64 x N=256; fp16 MFMA 16x16x32.
template<typename AT>
__global__ __launch_bounds__(256)
void gemm_xg(const AT* __restrict__ A, const _Float16* __restrict__ W16,
             const float* __restrict__ bias, _Float16* __restrict__ Cout)
{
  __shared__ __align__(16) _Float16 aL[64][72];   // +8 halves pad: frag reads 2-way max
  __shared__ __align__(16) _Float16 wL[256][72];
  const int tid  = threadIdx.x;
  const int wave = tid >> 6;
  const int lane = tid & 63;
  const int lr   = lane & 15;
  const int kg   = lane >> 4;
  const size_t m0 = (size_t)blockIdx.x * 64;

  float4v acc[4][4];
  #pragma unroll
  for (int a=0;a<4;a++)
    #pragma unroll
    for (int b=0;b<4;b++)
      acc[a][b] = float4v{0.f,0.f,0.f,0.f};

  for (int kc = 0; kc < KIN; kc += 64) {
    if constexpr (__is_same(AT, float)) {
      #pragma unroll
      for (int q=0;q<4;q++){
        int fi = tid + q*256;
        int r = fi >> 4, c4 = (fi & 15)*4;
        *reinterpret_cast<half4v*>(&aL[r][c4]) = ld4h(&A[(m0+(size_t)r)*KIN + kc + c4]);
      }
    } else {
      #pragma unroll
      for (int q=0;q<2;q++){
        int fi = tid + q*256;
        int r = fi >> 3, c8 = (fi & 7)*8;
        *reinterpret_cast<half8v*>(&aL[r][c8]) =
            *reinterpret_cast<const half8v*>(&A[(m0+(size_t)r)*KIN + kc + c8]);
      }
    }
    #pragma unroll
    for (int q=0;q<8;q++){
      int fi = tid + q*256;
      int n = fi >> 3, c8 = (fi & 7)*8;
      *reinterpret_cast<half8v*>(&wL[n][c8]) =
          *reinterpret_cast<const half8v*>(&W16[(size_t)n*KIN + kc + c8]);
    }
    __syncthreads();
    #pragma unroll
    for (int ks=0; ks<64; ks+=32){
      half8v af[4], bf[4];
      #pragma unroll
      for (int rt=0;rt<4;rt++)
        af[rt] = *reinterpret_cast<const half8v*>(&aL[rt*16+lr][ks + kg*8]);
      #pragma unroll
      for (int ct=0;ct<4;ct++)
        bf[ct] = *reinterpret_cast<const half8v*>(&wL[wave*64 + ct*16 + lr][ks + kg*8]);
      #pragma unroll
      for (int rt=0;rt<4;rt++)
        #pragma unroll
        for (int ct=0;ct<4;ct++)
          acc[rt][ct] = __builtin_amdgcn_mfma_f32_16x16x32_f16(af[rt], bf[ct], acc[rt][ct], 0,0,0);
    }
    __syncthreads();
  }
  // C/D layout: col = lane&15, row = (lane>>4)*4 + i
  #pragma unroll
  for (int ct=0;ct<4;ct++){
    const int col = wave*64 + ct*16 + lr;
    const float bv = bias[col];
    #pragma unroll
    for (int rt=0;rt<4;rt++){
      const size_t rbase = m0 + rt*16 + kg*4;
      #pragma unroll
      for (int i=0;i<4;i++)
        Cout[(rbase+(size_t)i)*NG + col] = (_Float16)(acc[rt][ct][i] + bv);
    }
  }
}

// LSTM scan: 1 batch row per 128-thread block (2 waves).
// Thread t owns gate rows t and t+128: t<64 -> (i_t, g_t); t>=64 -> (f_{t-64}, o_{t-64}).
// Blocks [0,gridF) run forward on xgF/whhF; blocks >= gridF run reverse on xgR/whhR.
// MODE 0: write h per t into x1 (fp16, col 0 fwd / 64 rev). MODE 1: write final h only.
template<int MODE>
__global__ __launch_bounds__(128)
void lstm_scan(const _Float16* __restrict__ xgF, const _Float16* __restrict__ xgR,
               int gridF,
               const _Float16* __restrict__ whhF, const _Float16* __restrict__ whhR,
               _Float16* __restrict__ x1out, float* __restrict__ hfin)
{
  const int tid = threadIdx.x;
  const bool rev = (int)blockIdx.x >= gridF;
  const int b = rev ? ((int)blockIdx.x - gridF) : (int)blockIdx.x;
  const _Float16* __restrict__ xg  = rev ? xgR : xgF;
  const _Float16* __restrict__ whh = rev ? whhR : whhF;
  const int g0 = tid;
  const int g1 = tid + 128;

  __shared__ __align__(16) _Float16 h16[64];
  __shared__ __align__(16) float act2[64][2];

  // w_hh rows g0,g1 in registers as half2 pairs (64 VGPRs)
  half2v w0[32], w1[32];
  #pragma unroll
  for (int q=0;q<8;q++){
    *reinterpret_cast<half8v*>(&w0[q*4]) =
        *reinterpret_cast<const half8v*>(&whh[(size_t)g0*64 + q*8]);
    *reinterpret_cast<half8v*>(&w1[q*4]) =
        *reinterpret_cast<const half8v*>(&whh[(size_t)g1*64 + q*8]);
  }
  if (tid < 64) h16[tid] = (_Float16)0.f;
  float c_r = 0.f, h_last = 0.f;
  __syncthreads();

  const _Float16* __restrict__ xgb = xg + (size_t)b*TT*NG;
  const int t0 = rev ? TT-1 : 0;
  const int t1 = rev ? TT-2 : 1;
  float curA = (float)xgb[(size_t)t0*NG + g0];
  float curB = (float)xgb[(size_t)t0*NG + g1];
  float nxA  = (float)xgb[(size_t)t1*NG + g0];
  float nxB  = (float)xgb[(size_t)t1*NG + g1];

  for (int tt=0; tt<TT; ++tt){
    const int t   = rev ? (TT-1-tt) : tt;
    const int tnn = (tt+2 < TT) ? (tt+2) : (TT-1);
    const int tp  = rev ? (TT-1-tnn) : tnn;
    float pfA = (float)xgb[(size_t)tp*NG + g0];
    float pfB = (float)xgb[(size_t)tp*NG + g1];

    // two accumulator chains per gate row
    float a0=0.f, b0=0.f, a1=0.f, b1=0.f;
    #pragma unroll
    for (int q=0;q<8;q++){
      half2v hh[4];
      *reinterpret_cast<half8v*>(&hh[0]) = *reinterpret_cast<const half8v*>(&h16[q*8]);
      a0 = fdot2_(w0[q*4+0], hh[0], a0);
      b0 = fdot2_(w0[q*4+1], hh[1], b0);
      a0 = fdot2_(w0[q*4+2], hh[2], a0);
      b0 = fdot2_(w0[q*4+3], hh[3], b0);
      a1 = fdot2_(w1[q*4+0], hh[0], a1);
      b1 = fdot2_(w1[q*4+1], hh[1], b1);
      a1 = fdot2_(w1[q*4+2], hh[2], a1);
      b1 = fdot2_(w1[q*4+3], hh[3], b1);
    }
    const float pre0 = curA + (a0 + b0);
    const float pre1 = curB + (a1 + b1);

    if (tid >= 64){                    // f, o  (wave-uniform branch)
      act2[tid-64][0] = sigmoid_(pre0);
      act2[tid-64][1] = sigmoid_(pre1);
    }
    float iv = 0.f, gv = 0.f;
    if (tid < 64){                     // i, g
      iv = sigmoid_(pre0);
      gv = tanh_(pre1);
    }
    __syncthreads();
    if (tid < 64){
      const float fv = act2[tid][0], ov = act2[tid][1];
      c_r = fv*c_r + iv*gv;
      const float h = ov * tanh_(c_r);
      h_last = h;
      h16[tid] = (_Float16)h;
      if constexpr (MODE==0)
        x1out[((size_t)b*TT + t)*128 + (rev ? 64 : 0) + tid] = (_Float16)h;
    }
    __syncthreads();
    curA = nxA; curB = nxB; nxA = pfA; nxB = pfB;
  }
  if constexpr (MODE==1){
    if (tid < 64) hfin[(size_t)b*64 + tid] = h_last;
  }
}

// Layer-1 reverse collapses to ONE step from zero state on x1[:,T-1]; fuse with FC.
__global__ __launch_bounds__(256)
void final_fuse(const _Float16* __restrict__ x1, const float* __restrict__ w_ih,
                const float* __restrict__ bvec, const float* __restrict__ hfin,
                const float* __restrict__ fcw, const float* __restrict__ fcb,
                float* __restrict__ out)
{
  const int b = blockIdx.x, tid = threadIdx.x;
  __shared__ float xs[128];
  __shared__ float act[256];
  __shared__ float hall[128];
  if (tid < 128) xs[tid] = (float)x1[((size_t)b*TT + (TT-1))*128 + tid];
  __syncthreads();
  float a = bvec[tid];
  #pragma unroll
  for (int kk=0;kk<32;kk++){
    float4v wv = *reinterpret_cast<const float4v*>(&w_ih[(size_t)tid*128 + kk*4]);
    a += wv[0]*xs[kk*4] + wv[1]*xs[kk*4+1] + wv[2]*xs[kk*4+2] + wv[3]*xs[kk*4+3];
  }
  const int grp = tid>>6;
  act[tid] = (grp==2) ? tanh_(a) : sigmoid_(a);
  __syncthreads();
  if (tid < 64) {
    float c = act[tid]*act[128+tid];        // c = i*g (c0 = 0)
    float h = act[192+tid]*tanh_(c);        // h = o*tanh(c)
    hall[64+tid] = h;
    hall[tid] = hfin[(size_t)b*64 + tid];
  }
  __syncthreads();
  if (tid < 3) {
    float acc2 = fcb[tid];
    for (int k=0;k<128;k++) acc2 += fcw[(size_t)tid*128 + k]*hall[k];
    out[(size_t)b*3 + tid] = acc2;
  }
}

extern "C" void kernel_launch(void* const* d_in, const int* in_sizes, int n_in,
                              void* d_out, int out_size, void* d_ws, size_t ws_size,
                              hipStream_t stream) {
  const float* x        = (const float*)d_in[0];
  const float* w_ih_l0f = (const float*)d_in[1];
  const float* w_hh_l0f = (const float*)d_in[2];
  const float* b_l0f    = (const float*)d_in[3];
  const float* w_ih_l0r = (const float*)d_in[4];
  const float* w_hh_l0r = (const float*)d_in[5];
  const float* b_l0r    = (const float*)d_in[6];
  const float* w_ih_l1f = (const float*)d_in[7];
  const float* w_hh_l1f = (const float*)d_in[8];
  const float* b_l1f    = (const float*)d_in[9];
  const float* w_ih_l1r = (const float*)d_in[10];
  const float* b_l1r    = (const float*)d_in[12];
  const float* fc_w     = (const float*)d_in[13];
  const float* fc_b     = (const float*)d_in[14];
  float* out = (float*)d_out;

  // workspace layout (bytes)
  const size_t XG_BYTES = (size_t)BB*TT*NG*2;      // 67,108,864 (fp16)
  const size_t X1_BYTES = (size_t)BB*TT*128*2;     // 33,554,432
  const size_t HF_BYTES = (size_t)BB*64*4;         //    131,072
  const size_t W16_BYTES = (size_t)147456*2;       //    294,912
  if (ws_size < 2*XG_BYTES + X1_BYTES + HF_BYTES + W16_BYTES) return;
  _Float16* xgF  = (_Float16*)d_ws;
  _Float16* xgR  = (_Float16*)((char*)d_ws + XG_BYTES);
  _Float16* x1   = (_Float16*)((char*)d_ws + 2*XG_BYTES);
  float*    hfin = (float*)   ((char*)d_ws + 2*XG_BYTES + X1_BYTES);
  _Float16* w16  = (_Float16*)((char*)d_ws + 2*XG_BYTES + X1_BYTES + HF_BYTES);
  _Float16* wih_l0f16 = w16;
  _Float16* wih_l0r16 = w16 + 32768;
  _Float16* wih_l1f16 = w16 + 65536;
  _Float16* whh_l0f16 = w16 + 98304;
  _Float16* whh_l0r16 = w16 + 114688;
  _Float16* whh_l1f16 = w16 + 131072;

  const int MBLK = (BB*TT)/64;  // 2048

  conv_weights<<<576, 256, 0, stream>>>(w_ih_l0f, w_ih_l0r, w_ih_l1f,
                                        w_hh_l0f, w_hh_l0r, w_hh_l1f, w16);
  // layer 0: both input GEMMs, then fused fwd+rev scan (1024 blocks = 4/CU)
  gemm_xg<float><<<MBLK, 256, 0, stream>>>(x, wih_l0f16, b_l0f, xgF);
  gemm_xg<float><<<MBLK, 256, 0, stream>>>(x, wih_l0r16, b_l0r, xgR);
  lstm_scan<0><<<1024, 128, 0, stream>>>(xgF, xgR, 512, whh_l0f16, whh_l0r16, x1, nullptr);
  // layer 1 forward (only final h needed)
  gemm_xg<_Float16><<<MBLK, 256, 0, stream>>>(x1, wih_l1f16, b_l1f, xgF);
  lstm_scan<1><<<512, 128, 0, stream>>>(xgF, nullptr, 512, whh_l1f16, nullptr, nullptr, hfin);
  // layer 1 reverse one-step + FC
  final_fuse<<<BB, 256, 0, stream>>>(x1, w_ih_l1r, b_l1r, hfin, fc_w, fc_b, out);
}

// Round 3
// 478.570 us; speedup vs baseline: 1.8760x; 1.0229x over previous
//
#include <hip/hip_runtime.h>

#define TT 256   // T
#define BB 512   // B
#define NG 256   // 4*H
#define KIN 128  // input width for both layers

typedef _Float16 half2v __attribute__((ext_vector_type(2)));
typedef _Float16 half4v __attribute__((ext_vector_type(4)));
typedef _Float16 half8v __attribute__((ext_vector_type(8)));
typedef float float4v __attribute__((ext_vector_type(4)));

__device__ __forceinline__ float sig_(float x){ return 1.f/(1.f+__expf(-x)); }
__device__ __forceinline__ float th_(float x){ return fmaf(2.f, 1.f/(1.f+__expf(-2.f*x)), -1.f); }

#if __has_builtin(__builtin_amdgcn_fdot2)
__device__ __forceinline__ float fdot2_(half2v a, half2v b, float c){
  return __builtin_amdgcn_fdot2(a, b, c, false);
}
#else
__device__ __forceinline__ float fdot2_(half2v a, half2v b, float c){
  return c + (float)a[0]*(float)b[0] + (float)a[1]*(float)b[1];
}
#endif

__device__ __forceinline__ half4v ld4h(const float* p){
  float4v v = *reinterpret_cast<const float4v*>(p);
  half4v h; h[0]=(_Float16)v[0]; h[1]=(_Float16)v[1]; h[2]=(_Float16)v[2]; h[3]=(_Float16)v[3];
  return h;
}

// ---- one-shot weight conversion fp32 -> fp16 into ws pool ----
// halves offsets: wih_l0f 0, wih_l0r 32768, wih_l1f 65536,
//                 whh_l0f 98304, whh_l0r 114688, whh_l1f 131072  (total 147456)
__global__ __launch_bounds__(256)
void conv_weights(const float* __restrict__ s0, const float* __restrict__ s1,
                  const float* __restrict__ s2, const float* __restrict__ s3,
                  const float* __restrict__ s4, const float* __restrict__ s5,
                  _Float16* __restrict__ dst)
{
  const int bid = blockIdx.x, tid = threadIdx.x;
  const float* src; int off, idx;
  if (bid < 128)      { src=s0; off=0;      idx=bid*256+tid; }
  else if (bid < 256) { src=s1; off=32768;  idx=(bid-128)*256+tid; }
  else if (bid < 384) { src=s2; off=65536;  idx=(bid-256)*256+tid; }
  else if (bid < 448) { src=s3; off=98304;  idx=(bid-384)*256+tid; }
  else if (bid < 512) { src=s4; off=114688; idx=(bid-448)*256+tid; }
  else                { src=s5; off=131072; idx=(bid-512)*256+tid; }
  dst[off+idx] = (_Float16)src[idx];
}

// C[m][n] = sum_k A[m][k]*W[n][k] + bias[n], written fp16.
// A: M x 128 (float or fp16), W16: 256x128 fp16 row-major.
// block 256 thr / 4 waves; tile M=64 x N=256; fp16 MFMA 16x16x32.
template<typename AT>
__global__ __launch_bounds__(256)
void gemm_xg(const AT* __restrict__ A, const _Float16* __restrict__ W16,
             const float* __restrict__ bias, _Float16* __restrict__ Cout)
{
  __shared__ __align__(16) _Float16 aL[64][72];   // +8 halves pad: conflict-free frag reads
  __shared__ __align__(16) _Float16 wL[256][72];
  const int tid  = threadIdx.x;
  const int wave = tid >> 6;
  const int lane = tid & 63;
  const int lr   = lane & 15;
  const int kg   = lane >> 4;
  const size_t m0 = (size_t)blockIdx.x * 64;

  float4v acc[4][4];
  #pragma unroll
  for (int a=0;a<4;a++)
    #pragma unroll
    for (int b=0;b<4;b++)
      acc[a][b] = float4v{0.f,0.f,0.f,0.f};

  for (int kc = 0; kc < KIN; kc += 64) {
    if constexpr (__is_same(AT, float)) {
      #pragma unroll
      for (int q=0;q<4;q++){
        int fi = tid + q*256;
        int r = fi >> 4, c4 = (fi & 15)*4;
        *reinterpret_cast<half4v*>(&aL[r][c4]) = ld4h(&A[(m0+(size_t)r)*KIN + kc + c4]);
      }
    } else {
      #pragma unroll
      for (int q=0;q<2;q++){
        int fi = tid + q*256;
        int r = fi >> 3, c8 = (fi & 7)*8;
        *reinterpret_cast<half8v*>(&aL[r][c8]) =
            *reinterpret_cast<const half8v*>(&A[(m0+(size_t)r)*KIN + kc + c8]);
      }
    }
    #pragma unroll
    for (int q=0;q<8;q++){
      int fi = tid + q*256;
      int n = fi >> 3, c8 = (fi & 7)*8;
      *reinterpret_cast<half8v*>(&wL[n][c8]) =
          *reinterpret_cast<const half8v*>(&W16[(size_t)n*KIN + kc + c8]);
    }
    __syncthreads();
    #pragma unroll
    for (int ks=0; ks<64; ks+=32){
      half8v af[4], bf[4];
      #pragma unroll
      for (int rt=0;rt<4;rt++)
        af[rt] = *reinterpret_cast<const half8v*>(&aL[rt*16+lr][ks + kg*8]);
      #pragma unroll
      for (int ct=0;ct<4;ct++)
        bf[ct] = *reinterpret_cast<const half8v*>(&wL[wave*64 + ct*16 + lr][ks + kg*8]);
      #pragma unroll
      for (int rt=0;rt<4;rt++)
        #pragma unroll
        for (int ct=0;ct<4;ct++)
          acc[rt][ct] = __builtin_amdgcn_mfma_f32_16x16x32_f16(af[rt], bf[ct], acc[rt][ct], 0,0,0);
    }
    __syncthreads();
  }
  // C/D layout: col = lane&15, row = (lane>>4)*4 + i
  #pragma unroll
  for (int ct=0;ct<4;ct++){
    const int col = wave*64 + ct*16 + lr;
    const float bv = bias[col];
    #pragma unroll
    for (int rt=0;rt<4;rt++){
      const size_t rbase = m0 + rt*16 + kg*4;
      #pragma unroll
      for (int i=0;i<4;i++)
        Cout[(rbase+(size_t)i)*NG + col] = (_Float16)(acc[rt][ct][i] + bv);
    }
  }
}

// LSTM scan: ONE WAVE per batch-row scan, zero barriers in the main loop.
// Lane j owns h_j, c_j and gate rows i_j=j, f_j=64+j, g_j=128+j, o_j=192+j.
// h broadcast via LDS: lane writes its h (b16), all lanes read all 64 h as 8x b128
// broadcast reads. Same-wave DS ops execute in order -> no s_barrier needed.
// Blocks [0,nF) forward on xgF/whhF; blocks >= nF reverse on xgR/whhR.
// MODE 0: write h per t into x1 (fp16, col 0 fwd / 64 rev). MODE 1: final h only.
template<int MODE>
__global__ __launch_bounds__(64)
void lstm_scan_w1(const _Float16* __restrict__ xgF, const _Float16* __restrict__ xgR,
                  int nF,
                  const _Float16* __restrict__ whhF, const _Float16* __restrict__ whhR,
                  _Float16* __restrict__ x1out, float* __restrict__ hfin)
{
  const int j = threadIdx.x;                 // 0..63
  const bool rev = (int)blockIdx.x >= nF;
  const int b = rev ? ((int)blockIdx.x - nF) : (int)blockIdx.x;
  const _Float16* __restrict__ xg  = rev ? xgR : xgF;
  const _Float16* __restrict__ whh = rev ? whhR : whhF;

  __shared__ __align__(16) _Float16 hs[64];

  // 4 gate rows of w_hh (64 halves each) -> 64 VGPRs total
  half2v wi[32], wf[32], wg[32], wo[32];
  #pragma unroll
  for (int q=0;q<8;q++){
    *reinterpret_cast<half8v*>(&wi[q*4]) = *reinterpret_cast<const half8v*>(&whh[(size_t)(      j)*64 + q*8]);
    *reinterpret_cast<half8v*>(&wf[q*4]) = *reinterpret_cast<const half8v*>(&whh[(size_t)( 64 + j)*64 + q*8]);
    *reinterpret_cast<half8v*>(&wg[q*4]) = *reinterpret_cast<const half8v*>(&whh[(size_t)(128 + j)*64 + q*8]);
    *reinterpret_cast<half8v*>(&wo[q*4]) = *reinterpret_cast<const half8v*>(&whh[(size_t)(192 + j)*64 + q*8]);
  }
  hs[j] = (_Float16)0.f;
  float c = 0.f, h_last = 0.f;
  __syncthreads();   // once: hs init visible

  const _Float16* __restrict__ xgb = xg + (size_t)b*TT*NG;
  const int tA = rev ? (TT-1) : 0;
  const int tB = rev ? (TT-2) : 1;
  float cur[4], nx[4];
  #pragma unroll
  for (int g=0; g<4; ++g){
    cur[g] = (float)xgb[(size_t)tA*NG + g*64 + j];
    nx[g]  = (float)xgb[(size_t)tB*NG + g*64 + j];
  }

  for (int tt=0; tt<TT; ++tt){
    const int t   = rev ? (TT-1-tt) : tt;
    const int tnn = (tt+2 < TT) ? (tt+2) : (TT-1);
    const int tp  = rev ? (TT-1-tnn) : tnn;
    float pf[4];
    #pragma unroll
    for (int g=0; g<4; ++g) pf[g] = (float)xgb[(size_t)tp*NG + g*64 + j];

    // broadcast-read all 64 h values (replicated in regs as half2 pairs)
    half2v h2[32];
    #pragma unroll
    for (int q=0;q<8;q++)
      *reinterpret_cast<half8v*>(&h2[q*4]) = *reinterpret_cast<const half8v*>(&hs[q*8]);

    // 4 gate-row dots, 2 fp32 chains each
    float ai=0.f, a2i=0.f, af=0.f, a2f=0.f, ag=0.f, a2g=0.f, ao=0.f, a2o=0.f;
    #pragma unroll
    for (int q=0;q<16;q++){
      half2v hA = h2[2*q], hB = h2[2*q+1];
      ai  = fdot2_(wi[2*q],   hA, ai);
      a2i = fdot2_(wi[2*q+1], hB, a2i);
      af  = fdot2_(wf[2*q],   hA, af);
      a2f = fdot2_(wf[2*q+1], hB, a2f);
      ag  = fdot2_(wg[2*q],   hA, ag);
      a2g = fdot2_(wg[2*q+1], hB, a2g);
      ao  = fdot2_(wo[2*q],   hA, ao);
      a2o = fdot2_(wo[2*q+1], hB, a2o);
    }
    const float iv = sig_(cur[0] + (ai + a2i));
    const float fv = sig_(cur[1] + (af + a2f));
    const float gv = th_ (cur[2] + (ag + a2g));
    const float ov = sig_(cur[3] + (ao + a2o));

    c = fv*c + iv*gv;
    const float h = ov * th_(c);
    h_last = h;
    hs[j] = (_Float16)h;                       // in-wave ordered vs next reads
    if constexpr (MODE==0)
      x1out[((size_t)b*TT + t)*128 + (rev ? 64 : 0) + j] = (_Float16)h;

    #pragma unroll
    for (int g=0; g<4; ++g){ cur[g] = nx[g]; nx[g] = pf[g]; }
  }
  if constexpr (MODE==1)
    hfin[(size_t)b*64 + j] = h_last;
}

// Layer-1 reverse collapses to ONE step from zero state on x1[:,T-1]; fuse with FC.
__global__ __launch_bounds__(256)
void final_fuse(const _Float16* __restrict__ x1, const float* __restrict__ w_ih,
                const float* __restrict__ bvec, const float* __restrict__ hfin,
                const float* __restrict__ fcw, const float* __restrict__ fcb,
                float* __restrict__ out)
{
  const int b = blockIdx.x, tid = threadIdx.x;
  __shared__ float xs[128];
  __shared__ float act[256];
  __shared__ float hall[128];
  if (tid < 128) xs[tid] = (float)x1[((size_t)b*TT + (TT-1))*128 + tid];
  __syncthreads();
  float a = bvec[tid];
  #pragma unroll
  for (int kk=0;kk<32;kk++){
    float4v wv = *reinterpret_cast<const float4v*>(&w_ih[(size_t)tid*128 + kk*4]);
    a += wv[0]*xs[kk*4] + wv[1]*xs[kk*4+1] + wv[2]*xs[kk*4+2] + wv[3]*xs[kk*4+3];
  }
  const int grp = tid>>6;
  act[tid] = (grp==2) ? th_(a) : sig_(a);
  __syncthreads();
  if (tid < 64) {
    float c = act[tid]*act[128+tid];        // c = i*g (c0 = 0)
    float h = act[192+tid]*th_(c);          // h = o*tanh(c)
    hall[64+tid] = h;
    hall[tid] = hfin[(size_t)b*64 + tid];
  }
  __syncthreads();
  if (tid < 3) {
    float acc2 = fcb[tid];
    for (int k=0;k<128;k++) acc2 += fcw[(size_t)tid*128 + k]*hall[k];
    out[(size_t)b*3 + tid] = acc2;
  }
}

extern "C" void kernel_launch(void* const* d_in, const int* in_sizes, int n_in,
                              void* d_out, int out_size, void* d_ws, size_t ws_size,
                              hipStream_t stream) {
  const float* x        = (const float*)d_in[0];
  const float* w_ih_l0f = (const float*)d_in[1];
  const float* w_hh_l0f = (const float*)d_in[2];
  const float* b_l0f    = (const float*)d_in[3];
  const float* w_ih_l0r = (const float*)d_in[4];
  const float* w_hh_l0r = (const float*)d_in[5];
  const float* b_l0r    = (const float*)d_in[6];
  const float* w_ih_l1f = (const float*)d_in[7];
  const float* w_hh_l1f = (const float*)d_in[8];
  const float* b_l1f    = (const float*)d_in[9];
  const float* w_ih_l1r = (const float*)d_in[10];
  const float* b_l1r    = (const float*)d_in[12];
  const float* fc_w     = (const float*)d_in[13];
  const float* fc_b     = (const float*)d_in[14];
  float* out = (float*)d_out;

  // workspace layout (bytes)
  const size_t XG_BYTES = (size_t)BB*TT*NG*2;      // 67,108,864 (fp16)
  const size_t X1_BYTES = (size_t)BB*TT*128*2;     // 33,554,432
  const size_t HF_BYTES = (size_t)BB*64*4;         //    131,072
  const size_t W16_BYTES = (size_t)147456*2;       //    294,912
  if (ws_size < 2*XG_BYTES + X1_BYTES + HF_BYTES + W16_BYTES) return;
  _Float16* xgF  = (_Float16*)d_ws;
  _Float16* xgR  = (_Float16*)((char*)d_ws + XG_BYTES);
  _Float16* x1   = (_Float16*)((char*)d_ws + 2*XG_BYTES);
  float*    hfin = (float*)   ((char*)d_ws + 2*XG_BYTES + X1_BYTES);
  _Float16* w16  = (_Float16*)((char*)d_ws + 2*XG_BYTES + X1_BYTES + HF_BYTES);
  _Float16* wih_l0f16 = w16;
  _Float16* wih_l0r16 = w16 + 32768;
  _Float16* wih_l1f16 = w16 + 65536;
  _Float16* whh_l0f16 = w16 + 98304;
  _Float16* whh_l0r16 = w16 + 114688;
  _Float16* whh_l1f16 = w16 + 131072;

  const int MBLK = (BB*TT)/64;  // 2048

  conv_weights<<<576, 256, 0, stream>>>(w_ih_l0f, w_ih_l0r, w_ih_l1f,
                                        w_hh_l0f, w_hh_l0r, w_hh_l1f, w16);
  // layer 0: both input GEMMs, then fused fwd+rev scan (1024 one-wave blocks)
  gemm_xg<float><<<MBLK, 256, 0, stream>>>(x, wih_l0f16, b_l0f, xgF);
  gemm_xg<float><<<MBLK, 256, 0, stream>>>(x, wih_l0r16, b_l0r, xgR);
  lstm_scan_w1<0><<<1024, 64, 0, stream>>>(xgF, xgR, 512, whh_l0f16, whh_l0r16, x1, nullptr);
  // layer 1 forward (only final h needed)
  gemm_xg<_Float16><<<MBLK, 256, 0, stream>>>(x1, wih_l1f16, b_l1f, xgF);
  lstm_scan_w1<1><<<512, 64, 0, stream>>>(xgF, nullptr, 512, whh_l1f16, nullptr, nullptr, hfin);
  // layer 1 reverse one-step + FC
  final_fuse<<<BB, 256, 0, stream>>>(x1, w_ih_l1r, b_l1r, hfin, fc_w, fc_b, out);
}

// Round 4
// 472.009 us; speedup vs baseline: 1.9021x; 1.0139x over previous
//
#include <hip/hip_runtime.h>

#define TT 256   // T
#define BB 512   // B
#define NG 256   // 4*H
#define KIN 128  // input width for both layers

typedef _Float16 half2v __attribute__((ext_vector_type(2)));
typedef _Float16 half4v __attribute__((ext_vector_type(4)));
typedef _Float16 half8v __attribute__((ext_vector_type(8)));
typedef float float4v __attribute__((ext_vector_type(4)));

__device__ __forceinline__ float sig_(float x){ return 1.f/(1.f+__expf(-x)); }
__device__ __forceinline__ float th_(float x){ return fmaf(2.f, 1.f/(1.f+__expf(-2.f*x)), -1.f); }

#if __has_builtin(__builtin_amdgcn_fdot2)
__device__ __forceinline__ float fdot2_(half2v a, half2v b, float c){
  return __builtin_amdgcn_fdot2(a, b, c, false);
}
#else
__device__ __forceinline__ float fdot2_(half2v a, half2v b, float c){
  return c + (float)a[0]*(float)b[0] + (float)a[1]*(float)b[1];
}
#endif

__device__ __forceinline__ half4v ld4h(const float* p){
  float4v v = *reinterpret_cast<const float4v*>(p);
  half4v h; h[0]=(_Float16)v[0]; h[1]=(_Float16)v[1]; h[2]=(_Float16)v[2]; h[3]=(_Float16)v[3];
  return h;
}

// ---- one-shot weight conversion fp32 -> fp16 into ws pool ----
__global__ __launch_bounds__(256)
void conv_weights(const float* __restrict__ s0, const float* __restrict__ s1,
                  const float* __restrict__ s2, const float* __restrict__ s3,
                  const float* __restrict__ s4, const float* __restrict__ s5,
                  _Float16* __restrict__ dst)
{
  const int bid = blockIdx.x, tid = threadIdx.x;
  const float* src; int off, idx;
  if (bid < 128)      { src=s0; off=0;      idx=bid*256+tid; }
  else if (bid < 256) { src=s1; off=32768;  idx=(bid-128)*256+tid; }
  else if (bid < 384) { src=s2; off=65536;  idx=(bid-256)*256+tid; }
  else if (bid < 448) { src=s3; off=98304;  idx=(bid-384)*256+tid; }
  else if (bid < 512) { src=s4; off=114688; idx=(bid-448)*256+tid; }
  else                { src=s5; off=131072; idx=(bid-512)*256+tid; }
  dst[off+idx] = (_Float16)src[idx];
}

// C[m][n] = sum_k A[m][k]*W[n][k] + bias[n], written fp16.
template<typename AT>
__global__ __launch_bounds__(256)
void gemm_xg(const AT* __restrict__ A, const _Float16* __restrict__ W16,
             const float* __restrict__ bias, _Float16* __restrict__ Cout)
{
  __shared__ __align__(16) _Float16 aL[64][72];
  __shared__ __align__(16) _Float16 wL[256][72];
  const int tid  = threadIdx.x;
  const int wave = tid >> 6;
  const int lane = tid & 63;
  const int lr   = lane & 15;
  const int kg   = lane >> 4;
  const size_t m0 = (size_t)blockIdx.x * 64;

  float4v acc[4][4];
  #pragma unroll
  for (int a=0;a<4;a++)
    #pragma unroll
    for (int b=0;b<4;b++)
      acc[a][b] = float4v{0.f,0.f,0.f,0.f};

  for (int kc = 0; kc < KIN; kc += 64) {
    if constexpr (__is_same(AT, float)) {
      #pragma unroll
      for (int q=0;q<4;q++){
        int fi = tid + q*256;
        int r = fi >> 4, c4 = (fi & 15)*4;
        *reinterpret_cast<half4v*>(&aL[r][c4]) = ld4h(&A[(m0+(size_t)r)*KIN + kc + c4]);
      }
    } else {
      #pragma unroll
      for (int q=0;q<2;q++){
        int fi = tid + q*256;
        int r = fi >> 3, c8 = (fi & 7)*8;
        *reinterpret_cast<half8v*>(&aL[r][c8]) =
            *reinterpret_cast<const half8v*>(&A[(m0+(size_t)r)*KIN + kc + c8]);
      }
    }
    #pragma unroll
    for (int q=0;q<8;q++){
      int fi = tid + q*256;
      int n = fi >> 3, c8 = (fi & 7)*8;
      *reinterpret_cast<half8v*>(&wL[n][c8]) =
          *reinterpret_cast<const half8v*>(&W16[(size_t)n*KIN + kc + c8]);
    }
    __syncthreads();
    #pragma unroll
    for (int ks=0; ks<64; ks+=32){
      half8v af[4], bf[4];
      #pragma unroll
      for (int rt=0;rt<4;rt++)
        af[rt] = *reinterpret_cast<const half8v*>(&aL[rt*16+lr][ks + kg*8]);
      #pragma unroll
      for (int ct=0;ct<4;ct++)
        bf[ct] = *reinterpret_cast<const half8v*>(&wL[wave*64 + ct*16 + lr][ks + kg*8]);
      #pragma unroll
      for (int rt=0;rt<4;rt++)
        #pragma unroll
        for (int ct=0;ct<4;ct++)
          acc[rt][ct] = __builtin_amdgcn_mfma_f32_16x16x32_f16(af[rt], bf[ct], acc[rt][ct], 0,0,0);
    }
    __syncthreads();
  }
  #pragma unroll
  for (int ct=0;ct<4;ct++){
    const int col = wave*64 + ct*16 + lr;
    const float bv = bias[col];
    #pragma unroll
    for (int rt=0;rt<4;rt++){
      const size_t rbase = m0 + rt*16 + kg*4;
      #pragma unroll
      for (int i=0;i<4;i++)
        Cout[(rbase+(size_t)i)*NG + col] = (_Float16)(acc[rt][ct][i] + bv);
    }
  }
}

// LSTM scan: ONE WAVE per row-scan, zero loop barriers.
// Fix vs r3: xg preacts prefetched distance-4 into an fp16 register ring with
// STATIC indices (unroll-4 inner). No f32 cvt at load site -> no vmcnt(0) per
// step; cvt happens 4 steps later with 12 newer loads outstanding.
template<int MODE>
__global__ __launch_bounds__(64)
void lstm_scan_w1(const _Float16* __restrict__ xgF, const _Float16* __restrict__ xgR,
                  int nF,
                  const _Float16* __restrict__ whhF, const _Float16* __restrict__ whhR,
                  _Float16* __restrict__ x1out, float* __restrict__ hfin)
{
  const int j = threadIdx.x;                 // 0..63
  const bool rev = (int)blockIdx.x >= nF;
  const int b = rev ? ((int)blockIdx.x - nF) : (int)blockIdx.x;
  const _Float16* __restrict__ xg  = rev ? xgR : xgF;
  const _Float16* __restrict__ whh = rev ? whhR : whhF;

  __shared__ __align__(16) _Float16 hs[64];

  half2v wi[32], wf[32], wg[32], wo[32];
  #pragma unroll
  for (int q=0;q<8;q++){
    *reinterpret_cast<half8v*>(&wi[q*4]) = *reinterpret_cast<const half8v*>(&whh[(size_t)(      j)*64 + q*8]);
    *reinterpret_cast<half8v*>(&wf[q*4]) = *reinterpret_cast<const half8v*>(&whh[(size_t)( 64 + j)*64 + q*8]);
    *reinterpret_cast<half8v*>(&wg[q*4]) = *reinterpret_cast<const half8v*>(&whh[(size_t)(128 + j)*64 + q*8]);
    *reinterpret_cast<half8v*>(&wo[q*4]) = *reinterpret_cast<const half8v*>(&whh[(size_t)(192 + j)*64 + q*8]);
  }
  hs[j] = (_Float16)0.f;
  float c = 0.f, h_last = 0.f;
  __syncthreads();   // once: hs init visible

  const _Float16* __restrict__ xgb = xg + (size_t)b*TT*NG + j;
  // byte-offset helper: step tt -> row offset (in halves)
  // forward: tt ; reverse: TT-1-tt
  _Float16 ring[4][4];   // [ring slot][gate]  -- all indices static after unroll
  #pragma unroll
  for (int u=0;u<4;u++){
    const size_t o = (size_t)(rev ? (TT-1-u) : u) * NG;
    #pragma unroll
    for (int g=0;g<4;g++) ring[u][g] = xgb[o + g*64];
  }

  for (int tb=0; tb<TT; tb+=4){
    #pragma unroll
    for (int u=0;u<4;u++){
      const int tt = tb + u;
      const int t  = rev ? (TT-1-tt) : tt;

      // consume slot u (loaded 4 steps ago); cvt here -> waits vmcnt(12), not 0
      const float x0 = (float)ring[u][0];
      const float x1v = (float)ring[u][1];
      const float x2 = (float)ring[u][2];
      const float x3 = (float)ring[u][3];

      // refill slot u for step tt+4
      const int tf = tt + 4;
      if (tf < TT){
        const size_t o = (size_t)(rev ? (TT-1-tf) : tf) * NG;
        #pragma unroll
        for (int g=0;g<4;g++) ring[u][g] = xgb[o + g*64];
      }

      // broadcast-read all 64 h values
      half2v h2[32];
      #pragma unroll
      for (int q=0;q<8;q++)
        *reinterpret_cast<half8v*>(&h2[q*4]) = *reinterpret_cast<const half8v*>(&hs[q*8]);

      float ai=0.f, a2i=0.f, af=0.f, a2f=0.f, ag=0.f, a2g=0.f, ao=0.f, a2o=0.f;
      #pragma unroll
      for (int q=0;q<16;q++){
        half2v hA = h2[2*q], hB = h2[2*q+1];
        ai  = fdot2_(wi[2*q],   hA, ai);
        a2i = fdot2_(wi[2*q+1], hB, a2i);
        af  = fdot2_(wf[2*q],   hA, af);
        a2f = fdot2_(wf[2*q+1], hB, a2f);
        ag  = fdot2_(wg[2*q],   hA, ag);
        a2g = fdot2_(wg[2*q+1], hB, a2g);
        ao  = fdot2_(wo[2*q],   hA, ao);
        a2o = fdot2_(wo[2*q+1], hB, a2o);
      }
      const float iv = sig_(x0  + (ai + a2i));
      const float fv = sig_(x1v + (af + a2f));
      const float gv = th_ (x2  + (ag + a2g));
      const float ov = sig_(x3  + (ao + a2o));

      c = fv*c + iv*gv;
      const float h = ov * th_(c);
      h_last = h;
      hs[j] = (_Float16)h;                       // in-wave ordered vs next reads
      if constexpr (MODE==0)
        x1out[((size_t)b*TT + t)*128 + (rev ? 64 : 0) + j] = (_Float16)h;
    }
  }
  if constexpr (MODE==1)
    hfin[(size_t)b*64 + j] = h_last;
}

// Layer-1 reverse collapses to ONE step from zero state on x1[:,T-1]; fuse with FC.
__global__ __launch_bounds__(256)
void final_fuse(const _Float16* __restrict__ x1, const float* __restrict__ w_ih,
                const float* __restrict__ bvec, const float* __restrict__ hfin,
                const float* __restrict__ fcw, const float* __restrict__ fcb,
                float* __restrict__ out)
{
  const int b = blockIdx.x, tid = threadIdx.x;
  __shared__ float xs[128];
  __shared__ float act[256];
  __shared__ float hall[128];
  if (tid < 128) xs[tid] = (float)x1[((size_t)b*TT + (TT-1))*128 + tid];
  __syncthreads();
  float a = bvec[tid];
  #pragma unroll
  for (int kk=0;kk<32;kk++){
    float4v wv = *reinterpret_cast<const float4v*>(&w_ih[(size_t)tid*128 + kk*4]);
    a += wv[0]*xs[kk*4] + wv[1]*xs[kk*4+1] + wv[2]*xs[kk*4+2] + wv[3]*xs[kk*4+3];
  }
  const int grp = tid>>6;
  act[tid] = (grp==2) ? th_(a) : sig_(a);
  __syncthreads();
  if (tid < 64) {
    float c = act[tid]*act[128+tid];        // c = i*g (c0 = 0)
    float h = act[192+tid]*th_(c);          // h = o*tanh(c)
    hall[64+tid] = h;
    hall[tid] = hfin[(size_t)b*64 + tid];
  }
  __syncthreads();
  if (tid < 3) {
    float acc2 = fcb[tid];
    for (int k=0;k<128;k++) acc2 += fcw[(size_t)tid*128 + k]*hall[k];
    out[(size_t)b*3 + tid] = acc2;
  }
}

extern "C" void kernel_launch(void* const* d_in, const int* in_sizes, int n_in,
                              void* d_out, int out_size, void* d_ws, size_t ws_size,
                              hipStream_t stream) {
  const float* x        = (const float*)d_in[0];
  const float* w_ih_l0f = (const float*)d_in[1];
  const float* w_hh_l0f = (const float*)d_in[2];
  const float* b_l0f    = (const float*)d_in[3];
  const float* w_ih_l0r = (const float*)d_in[4];
  const float* w_hh_l0r = (const float*)d_in[5];
  const float* b_l0r    = (const float*)d_in[6];
  const float* w_ih_l1f = (const float*)d_in[7];
  const float* w_hh_l1f = (const float*)d_in[8];
  const float* b_l1f    = (const float*)d_in[9];
  const float* w_ih_l1r = (const float*)d_in[10];
  const float* b_l1r    = (const float*)d_in[12];
  const float* fc_w     = (const float*)d_in[13];
  const float* fc_b     = (const float*)d_in[14];
  float* out = (float*)d_out;

  // workspace layout (bytes)
  const size_t XG_BYTES = (size_t)BB*TT*NG*2;      // 67,108,864 (fp16)
  const size_t X1_BYTES = (size_t)BB*TT*128*2;     // 33,554,432
  const size_t HF_BYTES = (size_t)BB*64*4;         //    131,072
  const size_t W16_BYTES = (size_t)147456*2;       //    294,912
  if (ws_size < 2*XG_BYTES + X1_BYTES + HF_BYTES + W16_BYTES) return;
  _Float16* xgF  = (_Float16*)d_ws;
  _Float16* xgR  = (_Float16*)((char*)d_ws + XG_BYTES);
  _Float16* x1   = (_Float16*)((char*)d_ws + 2*XG_BYTES);
  float*    hfin = (float*)   ((char*)d_ws + 2*XG_BYTES + X1_BYTES);
  _Float16* w16  = (_Float16*)((char*)d_ws + 2*XG_BYTES + X1_BYTES + HF_BYTES);
  _Float16* wih_l0f16 = w16;
  _Float16* wih_l0r16 = w16 + 32768;
  _Float16* wih_l1f16 = w16 + 65536;
  _Float16* whh_l0f16 = w16 + 98304;
  _Float16* whh_l0r16 = w16 + 114688;
  _Float16* whh_l1f16 = w16 + 131072;

  const int MBLK = (BB*TT)/64;  // 2048

  conv_weights<<<576, 256, 0, stream>>>(w_ih_l0f, w_ih_l0r, w_ih_l1f,
                                        w_hh_l0f, w_hh_l0r, w_hh_l1f, w16);
  // layer 0: both input GEMMs, then fused fwd+rev scan (1024 one-wave blocks)
  gemm_xg<float><<<MBLK, 256, 0, stream>>>(x, wih_l0f16, b_l0f, xgF);
  gemm_xg<float><<<MBLK, 256, 0, stream>>>(x, wih_l0r16, b_l0r, xgR);
  lstm_scan_w1<0><<<1024, 64, 0, stream>>>(xgF, xgR, 512, whh_l0f16, whh_l0r16, x1, nullptr);
  // layer 1 forward (only final h needed)
  gemm_xg<_Float16><<<MBLK, 256, 0, stream>>>(x1, wih_l1f16, b_l1f, xgF);
  lstm_scan_w1<1><<<512, 64, 0, stream>>>(xgF, nullptr, 512, whh_l1f16, nullptr, nullptr, hfin);
  // layer 1 reverse one-step + FC
  final_fuse<<<BB, 256, 0, stream>>>(x1, w_ih_l1r, b_l1r, hfin, fc_w, fc_b, out);
}